// Round 9
// baseline (166.507 us; speedup 1.0000x reference)
//
#include <hip/hip_runtime.h>

typedef __attribute__((ext_vector_type(8))) short short8;
typedef __attribute__((ext_vector_type(4))) float float4f;

#define PITCH 136   // shorts/row in LDS planes
#define ROWS 64     // rows per fwd block (weight stream amortization)
#define LOG_SLOPE -2.302585092994046f   // log(0.1)
#define LN2 0.6931471805599453f
#define NBLK 76     // 12 LU + 64 fwd
#define LDS_BYTES 69888
// ws layout (floats): [0] ticket | [2..13] logdet partials | [64..4159] counts
// [4160..5695] fp32 biases | [8192..] W hi/lo ushort planes
#define WS_BIAS 4160
#define WS_WPLANES 8192
#define NWELEM 196608   // 12 * 16384

__device__ __forceinline__ float bf2f(unsigned int u) {
    return __builtin_bit_cast(float, u << 16);
}
__device__ __forceinline__ unsigned short f2bf(float f) {
    unsigned int x = __builtin_bit_cast(unsigned int, f);
    x += 0x7fff + ((x >> 16) & 1);   // round-to-nearest-even
    return (unsigned short)(x >> 16);
}

template<int ISF32>
__device__ __forceinline__ float ldv(const void* p, int i) {
    if (ISF32) return ((const float*)p)[i];
    return bf2f(((const unsigned short*)p)[i]);
}

// Per-wave dtype sniff: fp32 weights read as u16 pairs have uniform-random
// mantissa halves; bf16 weights have exponent fields in a narrow band.
__device__ __forceinline__ int detect_f32(const unsigned short* W1u, int lane) {
    unsigned int u = W1u[lane * 2];
    unsigned int e = (u >> 7) & 0xFF;
    int bad = (e < 64) || (e > 135);
    return __ballot(bad) != 0ull;
}

__device__ __forceinline__ float4f mfma16(short8 a, short8 b, float4f c) {
    return __builtin_amdgcn_mfma_f32_16x16x32_bf16(a, b, c, 0, 0, 0);
}

__device__ __forceinline__ void split8(float4f a, float4f b, short8& hi, short8& lo) {
#pragma unroll
    for (int j = 0; j < 4; ++j) {
        float v = a[j]; unsigned short h = f2bf(v);
        hi[j] = (short)h; lo[j] = (short)f2bf(v - bf2f(h));
        v = b[j]; h = f2bf(v);
        hi[4 + j] = (short)h; lo[4 + j] = (short)f2bf(v - bf2f(h));
    }
}

// ---- prep: W -> bf16 hi/lo planes, biases -> fp32, zero ticket ----
__global__ void k_prep(const void* __restrict__ W1, const void* __restrict__ W2,
                       const void* __restrict__ W3, const void* __restrict__ b1,
                       const void* __restrict__ b2, const void* __restrict__ b3,
                       float* __restrict__ ws) {
    const int tid = threadIdx.x, bid = blockIdx.x;
    const int isf32 = detect_f32((const unsigned short*)W1, tid & 63);
    unsigned short* whi = (unsigned short*)(ws + WS_WPLANES);
    unsigned short* wlo = whi + NWELEM;
    if (bid < 96) {
        int s = (bid * 256 + tid) * 8;        // 96*256*8 = 196608
        int mat = s >> 14, off = s & 16383;   // mat = wsel*4 + layer
        int wsel = mat >> 2;
        const void* Wm = wsel == 0 ? W1 : (wsel == 1 ? W2 : W3);
        int src = (mat & 3) * 16384 + off;
        short8 hi, lo;
        if (isf32) {
            const float* p = (const float*)Wm + src;
            split8(*(const float4f*)p, *(const float4f*)(p + 4), hi, lo);
        } else {
            hi = *(const short8*)((const unsigned short*)Wm + src);
            lo = (short8){0, 0, 0, 0, 0, 0, 0, 0};
        }
        *(short8*)(whi + s) = hi;
        *(short8*)(wlo + s) = lo;
    } else {
        for (int e = tid; e < 1536; e += 256) {
            int bsel = e >> 9, idx = e & 511;
            const void* bp = bsel == 0 ? b1 : (bsel == 1 ? b2 : b3);
            ws[WS_BIAS + e] = isf32 ? ((const float*)bp)[idx]
                                    : bf2f(((const unsigned short*)bp)[idx]);
        }
        if (tid == 0) ((int*)ws)[0] = 0;   // finalize ticket
    }
}

// out[ROWS x 128] = act( in[ROWS x 128] @ W^T + bias ); hi/lo bf16 LDS planes.
// MODE 0: out = leaky(v) | 1: out(f32) += v | 2: out = leaky(v)+count | 3: count only
template<int MODE>
__device__ __forceinline__ void matvec(const unsigned short* inh, const unsigned short* inl,
                                       unsigned short* outh, unsigned short* outl,
                                       const unsigned short* __restrict__ whi,
                                       const unsigned short* __restrict__ wlo,
                                       const float* __restrict__ bias,
                                       int lane, int colb, int* cnt) {
    const int m = lane & 15, q = lane >> 4;
    const int c0 = colb + m, c1 = colb + 16 + m;
    float b0 = bias[c0], b1v = bias[c1];
    float4f acc[4][2];
#pragma unroll
    for (int rt = 0; rt < 4; ++rt) {
        acc[rt][0] = (float4f){b0, b0, b0, b0};
        acc[rt][1] = (float4f){b1v, b1v, b1v, b1v};
    }
    __syncthreads();   // previous epilogue's writes to `in` now visible
#pragma unroll
    for (int kk = 0; kk < 4; ++kk) {
        const int kc = kk * 32 + q * 8;
        short8 w0h = *(const short8*)(whi + c0 * 128 + kc);
        short8 w1h = *(const short8*)(whi + c1 * 128 + kc);
        short8 w0l = *(const short8*)(wlo + c0 * 128 + kc);
        short8 w1l = *(const short8*)(wlo + c1 * 128 + kc);
#pragma unroll
        for (int rt = 0; rt < 4; ++rt) {
            short8 xh = *(const short8*)(inh + (rt * 16 + m) * PITCH + kc);
            short8 xl = *(const short8*)(inl + (rt * 16 + m) * PITCH + kc);
            acc[rt][0] = mfma16(xh, w0h, acc[rt][0]);
            acc[rt][0] = mfma16(xl, w0h, acc[rt][0]);
            acc[rt][0] = mfma16(xh, w0l, acc[rt][0]);
            acc[rt][1] = mfma16(xh, w1h, acc[rt][1]);
            acc[rt][1] = mfma16(xl, w1h, acc[rt][1]);
            acc[rt][1] = mfma16(xh, w1l, acc[rt][1]);
        }
    }
    __syncthreads();   // all reads of `in` done; in-place epilogue safe
    int c[4][4];
#pragma unroll
    for (int rt = 0; rt < 4; ++rt) {
#pragma unroll
        for (int r = 0; r < 4; ++r) {
            float v0 = acc[rt][r >> 2 ? 0 : 0][0], vdum;  // (placeholder avoided below)
            (void)vdum;
            v0 = acc[rt][0][r];
            float v1 = acc[rt][1][r];
            int row = rt * 16 + q * 4 + r;
            int o0 = row * PITCH + c0, o1 = row * PITCH + c1;
            if (MODE == 1) {
                v0 += bf2f(outh[o0]) + bf2f(outl[o0]);
                v1 += bf2f(outh[o1]) + bf2f(outl[o1]);
            }
            if (MODE >= 2) c[rt][r] = (v0 <= 0.0f) + (v1 <= 0.0f);
            if (MODE == 0 || MODE == 2) {
                v0 = v0 > 0.0f ? v0 : 0.1f * v0;
                v1 = v1 > 0.0f ? v1 : 0.1f * v1;
            }
            if (MODE != 3) {
                unsigned short h0 = f2bf(v0);
                outh[o0] = h0; outl[o0] = f2bf(v0 - bf2f(h0));
                unsigned short h1 = f2bf(v1);
                outh[o1] = h1; outl[o1] = f2bf(v1 - bf2f(h1));
            }
        }
    }
    if (MODE >= 2) {
#pragma unroll
        for (int rt = 0; rt < 4; ++rt) {
#pragma unroll
            for (int r = 0; r < 4; ++r) {
                int cc = c[rt][r];
                cc += __shfl_xor(cc, 1);
                cc += __shfl_xor(cc, 2);
                cc += __shfl_xor(cc, 4);
                cc += __shfl_xor(cc, 8);
                if (m == 0) atomicAdd(&cnt[rt * 16 + q * 4 + r], cc);
            }
        }
    }
}

template<int ISF32>
__device__ __forceinline__ void fwd(int bid, int tid, int lane, char* ldsb,
                                    const void* x, const float* ws, void* out,
                                    float* wsw) {
    unsigned short* Xh = (unsigned short*)ldsb;
    unsigned short* Xl = Xh + ROWS * PITCH;
    unsigned short* Th = Xl + ROWS * PITCH;
    unsigned short* Tl = Th + ROWS * PITCH;
    int* cnt = (int*)(Tl + ROWS * PITCH);
    const unsigned short* whi = (const unsigned short*)(ws + WS_WPLANES);
    const unsigned short* wlo = whi + NWELEM;
    const float* bias = ws + WS_BIAS;
    const int r0 = bid * ROWS;
    for (int e = tid; e < ROWS * 128; e += 256) {
        int r = e >> 7, c = e & 127;
        float v = ldv<ISF32>(x, (r0 + r) * 128 + c);
        unsigned short h = f2bf(v);
        Xh[r * PITCH + c] = h;
        Xl[r * PITCH + c] = f2bf(v - bf2f(h));
    }
    if (tid < ROWS) cnt[tid] = 0;
    const int colb = (tid >> 6) * 32;
#pragma unroll 1
    for (int layer = 0; layer < 4; ++layer) {
        const unsigned short* w1h = whi + (0 + layer) * 16384;
        const unsigned short* w1l = wlo + (0 + layer) * 16384;
        const unsigned short* w2h = whi + (4 + layer) * 16384;
        const unsigned short* w2l = wlo + (4 + layer) * 16384;
        const unsigned short* w3h = whi + (8 + layer) * 16384;
        const unsigned short* w3l = wlo + (8 + layer) * 16384;
        const float* b1p = bias + layer * 128;
        const float* b2p = bias + 512 + layer * 128;
        const float* b3p = bias + 1024 + layer * 128;
        matvec<0>(Xh, Xl, Th, Tl, w1h, w1l, b1p, lane, colb, cnt);  // T = leaky(h1)
        matvec<0>(Th, Tl, Th, Tl, w2h, w2l, b2p, lane, colb, cnt);  // T = leaky(h2)
        matvec<1>(Th, Tl, Xh, Xl, w3h, w3l, b3p, lane, colb, cnt);  // X += f
        matvec<2>(Xh, Xl, Th, Tl, w1h, w1l, b1p, lane, colb, cnt);  // leaky(g1), count
        matvec<3>(Th, Tl, Th, Tl, w2h, w2l, b2p, lane, colb, cnt);  // count g2
    }
    __syncthreads();
    for (int e = tid; e < ROWS * 128; e += 256) {
        int r = e >> 7, c = e & 127;
        float v = bf2f(Xh[r * PITCH + c]) + bf2f(Xl[r * PITCH + c]);
        if (ISF32) ((float*)out)[(r0 + r) * 128 + c] = v;
        else ((unsigned short*)out)[(r0 + r) * 128 + c] = f2bf(v);
    }
    if (tid < ROWS) wsw[64 + r0 + tid] = (float)cnt[tid];
}

// ---- register-resident unpivoted LU: matrix lives in VGPRs, only the
// pivot row/column round-trips through LDS (double-buffered, 1 barrier/step).
// NOTE: no dynamic indexing of V[] anywhere — dynamic index demotes the
// whole array to scratch (round-6 regression: +3.6 MB WRITE_SIZE, 2.5x dur).
template<int ISF32>
__device__ __forceinline__ float lu_logdet(int id, int tid, float* lds,
        const void* W1, const void* W2, const void* W3) {
    const int wsel = id % 3;
    const void* Wm = (wsel == 0 ? W1 : (wsel == 1 ? W2 : W3));
    const int ofs = (id / 3) * 16384;
    const int tx = tid & 31, ty = tid >> 5;
    float* rowbuf = lds;        // [2][128]: pivot row k, cols 0..127
    float* colbuf = lds + 256;  // [2][128]: pivot col k, packed [ty*16+m]
    float4f V[16];              // A[ty+8m][4tx..4tx+3]
#pragma unroll
    for (int m = 0; m < 16; ++m) {
        int base = ofs + (ty + 8 * m) * 128 + 4 * tx;
        if (ISF32) {
            V[m] = *(const float4f*)((const float*)Wm + base);
        } else {
            ushort4 u = *(const ushort4*)((const unsigned short*)Wm + base);
            V[m] = (float4f){bf2f(u.x), bf2f(u.y), bf2f(u.z), bf2f(u.w)};
        }
    }
    // stage buffers for k = 0
    if (ty == 0) *(float4f*)&rowbuf[4 * tx] = V[0];
    if (tx == 0) {
#pragma unroll
        for (int m = 0; m < 16; ++m) colbuf[ty * 16 + m] = V[m][0];
    }
    __syncthreads();
    float logacc = 0.0f;
    for (int k = 0; k < 128; ++k) {
        const int buf = (k & 1) << 7;
        float akk = rowbuf[buf + k];                       // broadcast
        float4f rk = *(const float4f*)&rowbuf[buf + 4 * tx];
        float G[16];
        *(float4f*)&G[0]  = *(const float4f*)&colbuf[buf + ty * 16];
        *(float4f*)&G[4]  = *(const float4f*)&colbuf[buf + ty * 16 + 4];
        *(float4f*)&G[8]  = *(const float4f*)&colbuf[buf + ty * 16 + 8];
        *(float4f*)&G[12] = *(const float4f*)&colbuf[buf + ty * 16 + 12];
        float rp = 1.0f / akk;
        logacc += __log2f(fabsf(akk));   // redundant across threads; parallel
#pragma unroll
        for (int m = 0; m < 16; ++m) {
            int r = ty + 8 * m;
            float gg = (r > k) ? G[m] * rp : 0.0f;
            V[m][0] -= gg * rk[0]; V[m][1] -= gg * rk[1];
            V[m][2] -= gg * rk[2]; V[m][3] -= gg * rk[3];
        }
        if (k < 127) {
            const int nk = k + 1;
            const int nbuf = (nk & 1) << 7;
            // wave-uniform switch -> static V[m] stores (NO dynamic reg index)
            if (ty == (nk & 7)) {
                float4f* dst = (float4f*)&rowbuf[nbuf + 4 * tx];
                switch (nk >> 3) {
                case 0:  *dst = V[0];  break;
                case 1:  *dst = V[1];  break;
                case 2:  *dst = V[2];  break;
                case 3:  *dst = V[3];  break;
                case 4:  *dst = V[4];  break;
                case 5:  *dst = V[5];  break;
                case 6:  *dst = V[6];  break;
                case 7:  *dst = V[7];  break;
                case 8:  *dst = V[8];  break;
                case 9:  *dst = V[9];  break;
                case 10: *dst = V[10]; break;
                case 11: *dst = V[11]; break;
                case 12: *dst = V[12]; break;
                case 13: *dst = V[13]; break;
                case 14: *dst = V[14]; break;
                default: *dst = V[15]; break;
                }
            }
            if (tx == (nk >> 2)) {
                switch (nk & 3) {
                case 0:
#pragma unroll
                    for (int m = 0; m < 16; ++m) colbuf[nbuf + ty * 16 + m] = V[m][0];
                    break;
                case 1:
#pragma unroll
                    for (int m = 0; m < 16; ++m) colbuf[nbuf + ty * 16 + m] = V[m][1];
                    break;
                case 2:
#pragma unroll
                    for (int m = 0; m < 16; ++m) colbuf[nbuf + ty * 16 + m] = V[m][2];
                    break;
                default:
#pragma unroll
                    for (int m = 0; m < 16; ++m) colbuf[nbuf + ty * 16 + m] = V[m][3];
                }
            }
        }
        __syncthreads();   // one barrier per step
    }
    return logacc * LN2;
}

__global__ __launch_bounds__(256) void k_main(
        const void* __restrict__ x,
        const void* __restrict__ W1, const void* __restrict__ b1,
        const void* __restrict__ W2, const void* __restrict__ b2,
        const void* __restrict__ W3, const void* __restrict__ b3,
        void* __restrict__ out, float* __restrict__ ws) {
    extern __shared__ __align__(16) char ldsb[];   // 69,888 B dynamic
    __shared__ int s_last;
    const int tid = threadIdx.x;
    const int lane = tid & 63;
    const int isf32 = detect_f32((const unsigned short*)W1, lane);

    if (blockIdx.x < 12) {
        float ld = isf32 ? lu_logdet<1>(blockIdx.x, tid, (float*)ldsb, W1, W2, W3)
                         : lu_logdet<0>(blockIdx.x, tid, (float*)ldsb, W1, W2, W3);
        if (tid == 0) ws[2 + blockIdx.x] = ld;
    } else {
        const int bid = blockIdx.x - 12;
        if (isf32) fwd<1>(bid, tid, lane, ldsb, x, ws, out, ws);
        else       fwd<0>(bid, tid, lane, ldsb, x, ws, out, ws);
    }

    // ---- last-block finalize ----
    __threadfence();
    if (tid == 0) s_last = (atomicAdd((int*)ws, 1) == NBLK - 1);
    __syncthreads();
    if (!s_last) return;
    __threadfence();   // acquire: other blocks' ws writes now visible
    float s = 0.0f;
#pragma unroll
    for (int i = 0; i < 12; ++i) s += ws[2 + i];
    for (int b = tid; b < 4096; b += 256) {
        float v = s + LOG_SLOPE * ws[64 + b];
        if (isf32) ((float*)out)[524288 + b] = v;
        else ((unsigned short*)out)[524288 + b] = f2bf(v);
    }
}

extern "C" void kernel_launch(void* const* d_in, const int* in_sizes, int n_in,
                              void* d_out, int out_size, void* d_ws, size_t ws_size,
                              hipStream_t stream) {
    const void* x  = d_in[0];
    const void* W1 = d_in[1];
    const void* b1 = d_in[2];
    const void* W2 = d_in[3];
    const void* b2 = d_in[4];
    const void* W3 = d_in[5];
    const void* b3 = d_in[6];
    float* ws = (float*)d_ws;

    hipLaunchKernelGGL(k_prep, dim3(97), dim3(256), 0, stream,
                       W1, W2, W3, b1, b2, b3, ws);
    hipLaunchKernelGGL(k_main, dim3(NBLK), dim3(256), LDS_BYTES, stream,
                       x, W1, b1, W2, b2, W3, b3, d_out, ws);
}

// Round 10
// 143.699 us; speedup vs baseline: 1.1587x; 1.1587x over previous
//
#include <hip/hip_runtime.h>

typedef __attribute__((ext_vector_type(8))) short short8;
typedef __attribute__((ext_vector_type(4))) float float4f;

#define PITCH 136   // shorts/row in LDS planes
#define ROWS 32     // rows per fwd block
#define LOG_SLOPE -2.302585092994046f   // log(0.1)
#define LN2 0.6931471805599453f
#define NBLK 140    // 12 LU + 128 fwd
#define LDS_BYTES 69760   // 8 planes * 32*136*2 + 128 cnt
// ws layout (floats): [0] ticket | [2..13] logdet partials | [64..4159] counts
// [4160..5695] fp32 biases | [8192..] W hi/lo ushort planes
#define WS_BIAS 4160
#define WS_WPLANES 8192
#define NWELEM 196608   // 12 * 16384

__device__ __forceinline__ float bf2f(unsigned int u) {
    return __builtin_bit_cast(float, u << 16);
}
__device__ __forceinline__ unsigned short f2bf(float f) {
    unsigned int x = __builtin_bit_cast(unsigned int, f);
    x += 0x7fff + ((x >> 16) & 1);   // round-to-nearest-even
    return (unsigned short)(x >> 16);
}
__device__ __forceinline__ float4f vmsub(float4f a, float s, float4f b) {
    a[0] -= s * b[0]; a[1] -= s * b[1]; a[2] -= s * b[2]; a[3] -= s * b[3];
    return a;
}

template<int ISF32>
__device__ __forceinline__ float ldv(const void* p, int i) {
    if (ISF32) return ((const float*)p)[i];
    return bf2f(((const unsigned short*)p)[i]);
}

// Per-wave dtype sniff: fp32 weights read as u16 pairs have uniform-random
// mantissa halves; bf16 weights have exponent fields in a narrow band.
__device__ __forceinline__ int detect_f32(const unsigned short* W1u, int lane) {
    unsigned int u = W1u[lane * 2];
    unsigned int e = (u >> 7) & 0xFF;
    int bad = (e < 64) || (e > 135);
    return __ballot(bad) != 0ull;
}

__device__ __forceinline__ float4f mfma16(short8 a, short8 b, float4f c) {
    return __builtin_amdgcn_mfma_f32_16x16x32_bf16(a, b, c, 0, 0, 0);
}

__device__ __forceinline__ void split8(float4f a, float4f b, short8& hi, short8& lo) {
#pragma unroll
    for (int j = 0; j < 4; ++j) {
        float v = a[j]; unsigned short h = f2bf(v);
        hi[j] = (short)h; lo[j] = (short)f2bf(v - bf2f(h));
        v = b[j]; h = f2bf(v);
        hi[4 + j] = (short)h; lo[4 + j] = (short)f2bf(v - bf2f(h));
    }
}

// ---- prep: W -> bf16 hi/lo planes, biases -> fp32, zero ticket ----
__global__ void k_prep(const void* __restrict__ W1, const void* __restrict__ W2,
                       const void* __restrict__ W3, const void* __restrict__ b1,
                       const void* __restrict__ b2, const void* __restrict__ b3,
                       float* __restrict__ ws) {
    const int tid = threadIdx.x, bid = blockIdx.x;
    const int isf32 = detect_f32((const unsigned short*)W1, tid & 63);
    unsigned short* whi = (unsigned short*)(ws + WS_WPLANES);
    unsigned short* wlo = whi + NWELEM;
    if (bid < 96) {
        int s = (bid * 256 + tid) * 8;        // 96*256*8 = 196608
        int mat = s >> 14, off = s & 16383;   // mat = wsel*4 + layer
        int wsel = mat >> 2;
        const void* Wm = wsel == 0 ? W1 : (wsel == 1 ? W2 : W3);
        int src = (mat & 3) * 16384 + off;
        short8 hi, lo;
        if (isf32) {
            const float* p = (const float*)Wm + src;
            split8(*(const float4f*)p, *(const float4f*)(p + 4), hi, lo);
        } else {
            hi = *(const short8*)((const unsigned short*)Wm + src);
            lo = (short8){0, 0, 0, 0, 0, 0, 0, 0};
        }
        *(short8*)(whi + s) = hi;
        *(short8*)(wlo + s) = lo;
    } else {
        for (int e = tid; e < 1536; e += 256) {
            int bsel = e >> 9, idx = e & 511;
            const void* bp = bsel == 0 ? b1 : (bsel == 1 ? b2 : b3);
            ws[WS_BIAS + e] = isf32 ? ((const float*)bp)[idx]
                                    : bf2f(((const unsigned short*)bp)[idx]);
        }
        if (tid == 0) ((int*)ws)[0] = 0;   // finalize ticket
    }
}

// out[ROWS x 128] = act( in[ROWS x 128] @ W^T + bias ); ping-pong planes,
// ONE barrier per matvec (entry). in/out/res planes are always distinct.
// MODE 0: out = leaky(v) | 1: out = res + v | 2: out = leaky(v)+count | 3: count only
template<int MODE>
__device__ __forceinline__ void matvec(
        const unsigned short* inh, const unsigned short* inl,
        unsigned short* outh, unsigned short* outl,
        const unsigned short* resh, const unsigned short* resl,
        const unsigned short* __restrict__ whi,
        const unsigned short* __restrict__ wlo,
        const float* __restrict__ bias,
        int lane, int colb, int* cnt) {
    const int m = lane & 15, q = lane >> 4;
    const int c0 = colb + m, c1 = colb + 16 + m;
    float b0 = bias[c0], b1v = bias[c1];
    float4f acc[2][2];
#pragma unroll
    for (int rt = 0; rt < 2; ++rt) {
        acc[rt][0] = (float4f){b0, b0, b0, b0};
        acc[rt][1] = (float4f){b1v, b1v, b1v, b1v};
    }
    __syncthreads();   // previous matvec's writes now visible
#pragma unroll
    for (int kk = 0; kk < 4; ++kk) {
        const int kc = kk * 32 + q * 8;
        short8 w0h = *(const short8*)(whi + c0 * 128 + kc);
        short8 w1h = *(const short8*)(whi + c1 * 128 + kc);
        short8 w0l = *(const short8*)(wlo + c0 * 128 + kc);
        short8 w1l = *(const short8*)(wlo + c1 * 128 + kc);
#pragma unroll
        for (int rt = 0; rt < 2; ++rt) {
            short8 xh = *(const short8*)(inh + (rt * 16 + m) * PITCH + kc);
            short8 xl = *(const short8*)(inl + (rt * 16 + m) * PITCH + kc);
            acc[rt][0] = mfma16(xh, w0h, acc[rt][0]);
            acc[rt][0] = mfma16(xl, w0h, acc[rt][0]);
            acc[rt][0] = mfma16(xh, w0l, acc[rt][0]);
            acc[rt][1] = mfma16(xh, w1h, acc[rt][1]);
            acc[rt][1] = mfma16(xl, w1h, acc[rt][1]);
            acc[rt][1] = mfma16(xh, w1l, acc[rt][1]);
        }
    }
    int c[2][4];
#pragma unroll
    for (int rt = 0; rt < 2; ++rt) {
#pragma unroll
        for (int r = 0; r < 4; ++r) {
            float v0 = acc[rt][0][r], v1 = acc[rt][1][r];
            int row = rt * 16 + q * 4 + r;
            int o0 = row * PITCH + c0, o1 = row * PITCH + c1;
            if (MODE == 1) {
                v0 += bf2f(resh[o0]) + bf2f(resl[o0]);
                v1 += bf2f(resh[o1]) + bf2f(resl[o1]);
            }
            if (MODE >= 2) c[rt][r] = (v0 <= 0.0f) + (v1 <= 0.0f);
            if (MODE == 0 || MODE == 2) {
                v0 = v0 > 0.0f ? v0 : 0.1f * v0;
                v1 = v1 > 0.0f ? v1 : 0.1f * v1;
            }
            if (MODE != 3) {
                unsigned short h0 = f2bf(v0);
                outh[o0] = h0; outl[o0] = f2bf(v0 - bf2f(h0));
                unsigned short h1 = f2bf(v1);
                outh[o1] = h1; outl[o1] = f2bf(v1 - bf2f(h1));
            }
        }
    }
    if (MODE >= 2) {
#pragma unroll
        for (int rt = 0; rt < 2; ++rt) {
#pragma unroll
            for (int r = 0; r < 4; ++r) {
                int cc = c[rt][r];
                cc += __shfl_xor(cc, 1);
                cc += __shfl_xor(cc, 2);
                cc += __shfl_xor(cc, 4);
                cc += __shfl_xor(cc, 8);
                if (m == 0) atomicAdd(&cnt[rt * 16 + q * 4 + r], cc);
            }
        }
    }
}

template<int ISF32>
__device__ __forceinline__ void fwd(int bid, int tid, int lane, char* ldsb,
                                    const void* x, const float* ws, void* out,
                                    float* wsw) {
    unsigned short* P = (unsigned short*)ldsb;
    unsigned short* Ah = P;
    unsigned short* Al = P + 1 * ROWS * PITCH;
    unsigned short* Bh = P + 2 * ROWS * PITCH;
    unsigned short* Bl = P + 3 * ROWS * PITCH;
    unsigned short* Th = P + 4 * ROWS * PITCH;
    unsigned short* Tl = P + 5 * ROWS * PITCH;
    unsigned short* Uh = P + 6 * ROWS * PITCH;
    unsigned short* Ul = P + 7 * ROWS * PITCH;
    int* cnt = (int*)(P + 8 * ROWS * PITCH);
    const unsigned short* whi = (const unsigned short*)(ws + WS_WPLANES);
    const unsigned short* wlo = whi + NWELEM;
    const float* bias = ws + WS_BIAS;
    const int r0 = bid * ROWS;
    for (int e = tid; e < ROWS * 128; e += 256) {
        int r = e >> 7, c = e & 127;
        float v = ldv<ISF32>(x, (r0 + r) * 128 + c);
        unsigned short h = f2bf(v);
        Ah[r * PITCH + c] = h;
        Al[r * PITCH + c] = f2bf(v - bf2f(h));
    }
    if (tid < ROWS) cnt[tid] = 0;
    const int colb = (tid >> 6) * 32;
    unsigned short *curh = Ah, *curl = Al, *othh = Bh, *othl = Bl;
#pragma unroll 1
    for (int layer = 0; layer < 4; ++layer) {
        const unsigned short* w1h = whi + (0 + layer) * 16384;
        const unsigned short* w1l = wlo + (0 + layer) * 16384;
        const unsigned short* w2h = whi + (4 + layer) * 16384;
        const unsigned short* w2l = wlo + (4 + layer) * 16384;
        const unsigned short* w3h = whi + (8 + layer) * 16384;
        const unsigned short* w3l = wlo + (8 + layer) * 16384;
        const float* b1p = bias + layer * 128;
        const float* b2p = bias + 512 + layer * 128;
        const float* b3p = bias + 1024 + layer * 128;
        matvec<0>(curh, curl, Th, Tl, 0, 0, w1h, w1l, b1p, lane, colb, cnt);
        matvec<0>(Th, Tl, Uh, Ul, 0, 0, w2h, w2l, b2p, lane, colb, cnt);
        matvec<1>(Uh, Ul, othh, othl, curh, curl, w3h, w3l, b3p, lane, colb, cnt);
        matvec<2>(othh, othl, Th, Tl, 0, 0, w1h, w1l, b1p, lane, colb, cnt);
        matvec<3>(Th, Tl, Th, Tl, 0, 0, w2h, w2l, b2p, lane, colb, cnt);
        unsigned short* t;
        t = curh; curh = othh; othh = t;
        t = curl; curl = othl; othl = t;
    }
    __syncthreads();
    for (int e = tid; e < ROWS * 128; e += 256) {
        int r = e >> 7, c = e & 127;
        float v = bf2f(curh[r * PITCH + c]) + bf2f(curl[r * PITCH + c]);
        if (ISF32) ((float*)out)[(r0 + r) * 128 + c] = v;
        else ((unsigned short*)out)[(r0 + r) * 128 + c] = f2bf(v);
    }
    if (tid < ROWS) wsw[64 + r0 + tid] = (float)cnt[tid];
}

// ---- register-resident unpivoted LU, RANK-4 per barrier (32 intervals).
// Per interval: stage 4 pivot rows + 4 pivot cols (double-buffered LDS);
// every thread redundantly factors the 4x4 diagonal block in registers and
// applies one rank-4 update to its V[16]. All register indices compile-time.
template<int ISF32>
__device__ __forceinline__ float lu_logdet(int id, int tid, float* lds,
        const void* W1, const void* W2, const void* W3) {
    const int wsel = id % 3;
    const void* Wm = (wsel == 0 ? W1 : (wsel == 1 ? W2 : W3));
    const int ofs = (id / 3) * 16384;
    const int tx = tid & 31, ty = tid >> 5;
    float* rowbuf = lds;          // [2][4][128]: rows K..K+3
    float* colbuf = lds + 1024;   // [2][4][128]: cols K..K+3 packed [j][ty*16+m]
    float4f V[16];                // A[ty+8m][4tx..4tx+3]
#pragma unroll
    for (int m = 0; m < 16; ++m) {
        int base = ofs + (ty + 8 * m) * 128 + 4 * tx;
        if (ISF32) {
            V[m] = *(const float4f*)((const float*)Wm + base);
        } else {
            ushort4 u = *(const ushort4*)((const unsigned short*)Wm + base);
            V[m] = (float4f){bf2f(u.x), bf2f(u.y), bf2f(u.z), bf2f(u.w)};
        }
    }
    // stage interval 0: rows 0..3 (ty 0..3, all m=0), cols 0..3 (owner tx==0)
    if (ty < 4) *(float4f*)&rowbuf[ty * 128 + 4 * tx] = V[0];
    if (tx == 0) {
#pragma unroll
        for (int j = 0; j < 4; ++j) {
#pragma unroll
            for (int mg = 0; mg < 4; ++mg) {
                float4f t = {V[mg * 4 + 0][j], V[mg * 4 + 1][j],
                             V[mg * 4 + 2][j], V[mg * 4 + 3][j]};
                *(float4f*)&colbuf[j * 128 + ty * 16 + mg * 4] = t;
            }
        }
    }
    __syncthreads();
    float logacc = 0.0f;
#pragma unroll 1
    for (int kap = 0; kap < 32; ++kap) {
        const int K = kap * 4;
        const int buf = (kap & 1) * 512;
        float4f D[4], R[4], C[4][4];
#pragma unroll
        for (int j = 0; j < 4; ++j) {
            D[j] = *(const float4f*)&rowbuf[buf + j * 128 + K];       // broadcast
            R[j] = *(const float4f*)&rowbuf[buf + j * 128 + 4 * tx];
#pragma unroll
            for (int mg = 0; mg < 4; ++mg)
                C[j][mg] = *(const float4f*)&colbuf[buf + j * 128 + ty * 16 + mg * 4];
        }
        // 4x4 panel factorization, redundant per thread
        float p0 = D[0][0], i0 = 1.0f / p0;
        float l10 = D[1][0] * i0, l20 = D[2][0] * i0, l30 = D[3][0] * i0;
        D[1] = vmsub(D[1], l10, D[0]); R[1] = vmsub(R[1], l10, R[0]);
        D[2] = vmsub(D[2], l20, D[0]); R[2] = vmsub(R[2], l20, R[0]);
        D[3] = vmsub(D[3], l30, D[0]); R[3] = vmsub(R[3], l30, R[0]);
        float p1 = D[1][1], i1 = 1.0f / p1;
        float l21 = D[2][1] * i1, l31 = D[3][1] * i1;
        D[2] = vmsub(D[2], l21, D[1]); R[2] = vmsub(R[2], l21, R[1]);
        D[3] = vmsub(D[3], l31, D[1]); R[3] = vmsub(R[3], l31, R[1]);
        float p2 = D[2][2], i2 = 1.0f / p2;
        float l32 = D[3][2] * i2;
        D[3] = vmsub(D[3], l32, D[2]); R[3] = vmsub(R[3], l32, R[2]);
        float p3 = D[3][3], i3 = 1.0f / p3;
        logacc += __log2f(fabsf(p0)) + __log2f(fabsf(p1))
                + __log2f(fabsf(p2)) + __log2f(fabsf(p3));
        float iv[4] = {i0, i1, i2, i3};
        // cols -> multipliers in place (masked per row), propagate to later cols
#pragma unroll
        for (int i = 0; i < 4; ++i) {
#pragma unroll
            for (int mg = 0; mg < 4; ++mg) {
#pragma unroll
                for (int e = 0; e < 4; ++e) {
                    int r = ty + 32 * mg + 8 * e;
                    C[i][mg][e] = (r > K + i) ? C[i][mg][e] * iv[i] : 0.0f;
                }
            }
#pragma unroll
            for (int j = i + 1; j < 4; ++j) {
                float uij = D[i][j];
#pragma unroll
                for (int mg = 0; mg < 4; ++mg)
                    C[j][mg] = vmsub(C[j][mg], uij, C[i][mg]);
            }
        }
        // rank-4 trailing update
#pragma unroll
        for (int mg = 0; mg < 4; ++mg) {
#pragma unroll
            for (int e = 0; e < 4; ++e) {
                float4f v = V[mg * 4 + e];
                v = vmsub(v, C[0][mg][e], R[0]);
                v = vmsub(v, C[1][mg][e], R[1]);
                v = vmsub(v, C[2][mg][e], R[2]);
                v = vmsub(v, C[3][mg][e], R[3]);
                V[mg * 4 + e] = v;
            }
        }
        // stage next interval (rows/cols K+4..K+7)
        if (kap < 31) {
            const int nbuf = ((kap + 1) & 1) * 512;
            const int tb = (kap & 1) ? 0 : 4;     // rows K+4..K+7 -> ty in [tb,tb+4)
            const int mn = (kap + 1) >> 1;        // their m index (uniform)
            if (ty >= tb && ty < tb + 4) {
                float4f val;
                switch (mn) {                     // uniform switch, static reg index
                case 0:  val = V[0];  break; case 1:  val = V[1];  break;
                case 2:  val = V[2];  break; case 3:  val = V[3];  break;
                case 4:  val = V[4];  break; case 5:  val = V[5];  break;
                case 6:  val = V[6];  break; case 7:  val = V[7];  break;
                case 8:  val = V[8];  break; case 9:  val = V[9];  break;
                case 10: val = V[10]; break; case 11: val = V[11]; break;
                case 12: val = V[12]; break; case 13: val = V[13]; break;
                case 14: val = V[14]; break; default: val = V[15]; break;
                }
                *(float4f*)&rowbuf[nbuf + (ty - tb) * 128 + 4 * tx] = val;
            }
            if (tx == kap + 1) {   // owner of cols K+4..K+7 (4-aligned)
#pragma unroll
                for (int j = 0; j < 4; ++j) {
#pragma unroll
                    for (int mg = 0; mg < 4; ++mg) {
                        float4f t = {V[mg * 4 + 0][j], V[mg * 4 + 1][j],
                                     V[mg * 4 + 2][j], V[mg * 4 + 3][j]};
                        *(float4f*)&colbuf[nbuf + j * 128 + ty * 16 + mg * 4] = t;
                    }
                }
            }
        }
        __syncthreads();   // one barrier per 4 pivots
    }
    return logacc * LN2;
}

__global__ __launch_bounds__(256) void k_main(
        const void* __restrict__ x,
        const void* __restrict__ W1, const void* __restrict__ b1,
        const void* __restrict__ W2, const void* __restrict__ b2,
        const void* __restrict__ W3, const void* __restrict__ b3,
        void* __restrict__ out, float* __restrict__ ws) {
    extern __shared__ __align__(16) char ldsb[];
    __shared__ int s_last;
    const int tid = threadIdx.x;
    const int lane = tid & 63;
    const int isf32 = detect_f32((const unsigned short*)W1, lane);

    if (blockIdx.x < 12) {
        float ld = isf32 ? lu_logdet<1>(blockIdx.x, tid, (float*)ldsb, W1, W2, W3)
                         : lu_logdet<0>(blockIdx.x, tid, (float*)ldsb, W1, W2, W3);
        if (tid == 0) ws[2 + blockIdx.x] = ld;
    } else {
        const int bid = blockIdx.x - 12;
        if (isf32) fwd<1>(bid, tid, lane, ldsb, x, ws, out, ws);
        else       fwd<0>(bid, tid, lane, ldsb, x, ws, out, ws);
    }

    // ---- last-block finalize ----
    __threadfence();
    if (tid == 0) s_last = (atomicAdd((int*)ws, 1) == NBLK - 1);
    __syncthreads();
    if (!s_last) return;
    __threadfence();   // acquire: other blocks' ws writes now visible
    float s = 0.0f;
#pragma unroll
    for (int i = 0; i < 12; ++i) s += ws[2 + i];
    for (int b = tid; b < 4096; b += 256) {
        float v = s + LOG_SLOPE * ws[64 + b];
        if (isf32) ((float*)out)[524288 + b] = v;
        else ((unsigned short*)out)[524288 + b] = f2bf(v);
    }
}

extern "C" void kernel_launch(void* const* d_in, const int* in_sizes, int n_in,
                              void* d_out, int out_size, void* d_ws, size_t ws_size,
                              hipStream_t stream) {
    const void* x  = d_in[0];
    const void* W1 = d_in[1];
    const void* b1 = d_in[2];
    const void* W2 = d_in[3];
    const void* b2 = d_in[4];
    const void* W3 = d_in[5];
    const void* b3 = d_in[6];
    float* ws = (float*)d_ws;

    hipLaunchKernelGGL(k_prep, dim3(97), dim3(256), 0, stream,
                       W1, W2, W3, b1, b2, b3, ws);
    hipLaunchKernelGGL(k_main, dim3(NBLK), dim3(256), LDS_BYTES, stream,
                       x, W1, b1, W2, b2, W3, b3, d_out, ws);
}

// Round 11
// 136.506 us; speedup vs baseline: 1.2198x; 1.0527x over previous
//
#include <hip/hip_runtime.h>

typedef __attribute__((ext_vector_type(8))) short short8;
typedef __attribute__((ext_vector_type(4))) float float4f;

#define PITCH 136   // shorts/row in LDS planes
#define ROWS 32     // rows per fwd block
#define LOG_SLOPE -2.302585092994046f   // log(0.1)
#define LN2 0.6931471805599453f
#define NBLK 140    // 12 LU + 128 fwd
#define LDS_BYTES 69760   // 8 planes * 32*136*2 + 128 cnt
// ws layout (floats): [0] ticket | [2..13] logdet partials | [64..4159] counts
// [4160..5695] fp32 biases | [8192..] W hi/lo ushort planes
#define WS_BIAS 4160
#define WS_WPLANES 8192
#define NWELEM 196608   // 12 * 16384

__device__ __forceinline__ float bf2f(unsigned int u) {
    return __builtin_bit_cast(float, u << 16);
}
__device__ __forceinline__ unsigned short f2bf(float f) {
    unsigned int x = __builtin_bit_cast(unsigned int, f);
    x += 0x7fff + ((x >> 16) & 1);   // round-to-nearest-even
    return (unsigned short)(x >> 16);
}
__device__ __forceinline__ float4f vmsub(float4f a, float s, float4f b) {
    a[0] -= s * b[0]; a[1] -= s * b[1]; a[2] -= s * b[2]; a[3] -= s * b[3];
    return a;
}

template<int ISF32>
__device__ __forceinline__ float ldv(const void* p, int i) {
    if (ISF32) return ((const float*)p)[i];
    return bf2f(((const unsigned short*)p)[i]);
}

// Per-wave dtype sniff: fp32 weights read as u16 pairs have uniform-random
// mantissa halves; bf16 weights have exponent fields in a narrow band.
__device__ __forceinline__ int detect_f32(const unsigned short* W1u, int lane) {
    unsigned int u = W1u[lane * 2];
    unsigned int e = (u >> 7) & 0xFF;
    int bad = (e < 64) || (e > 135);
    return __ballot(bad) != 0ull;
}

__device__ __forceinline__ float4f mfma16(short8 a, short8 b, float4f c) {
    return __builtin_amdgcn_mfma_f32_16x16x32_bf16(a, b, c, 0, 0, 0);
}

__device__ __forceinline__ void split8(float4f a, float4f b, short8& hi, short8& lo) {
#pragma unroll
    for (int j = 0; j < 4; ++j) {
        float v = a[j]; unsigned short h = f2bf(v);
        hi[j] = (short)h; lo[j] = (short)f2bf(v - bf2f(h));
        v = b[j]; h = f2bf(v);
        hi[4 + j] = (short)h; lo[4 + j] = (short)f2bf(v - bf2f(h));
    }
}

// ---- prep: W -> bf16 hi/lo planes, biases -> fp32, zero ticket ----
__global__ void k_prep(const void* __restrict__ W1, const void* __restrict__ W2,
                       const void* __restrict__ W3, const void* __restrict__ b1,
                       const void* __restrict__ b2, const void* __restrict__ b3,
                       float* __restrict__ ws) {
    const int tid = threadIdx.x, bid = blockIdx.x;
    const int isf32 = detect_f32((const unsigned short*)W1, tid & 63);
    unsigned short* whi = (unsigned short*)(ws + WS_WPLANES);
    unsigned short* wlo = whi + NWELEM;
    if (bid < 96) {
        int s = (bid * 256 + tid) * 8;        // 96*256*8 = 196608
        int mat = s >> 14, off = s & 16383;   // mat = wsel*4 + layer
        int wsel = mat >> 2;
        const void* Wm = wsel == 0 ? W1 : (wsel == 1 ? W2 : W3);
        int src = (mat & 3) * 16384 + off;
        short8 hi, lo;
        if (isf32) {
            const float* p = (const float*)Wm + src;
            split8(*(const float4f*)p, *(const float4f*)(p + 4), hi, lo);
        } else {
            hi = *(const short8*)((const unsigned short*)Wm + src);
            lo = (short8){0, 0, 0, 0, 0, 0, 0, 0};
        }
        *(short8*)(whi + s) = hi;
        *(short8*)(wlo + s) = lo;
    } else {
        for (int e = tid; e < 1536; e += 256) {
            int bsel = e >> 9, idx = e & 511;
            const void* bp = bsel == 0 ? b1 : (bsel == 1 ? b2 : b3);
            ws[WS_BIAS + e] = isf32 ? ((const float*)bp)[idx]
                                    : bf2f(((const unsigned short*)bp)[idx]);
        }
        if (tid == 0) ((int*)ws)[0] = 0;   // finalize ticket
    }
}

// Weight fragment set for one matvec: [kk]{w0h,w1h,w0l,w1l}. All static indices.
struct W8 { short8 v[16]; };

__device__ __forceinline__ W8 loadW(const unsigned short* __restrict__ wh,
                                    const unsigned short* __restrict__ wl,
                                    int c0, int c1, int q) {
    W8 r;
#pragma unroll
    for (int kk = 0; kk < 4; ++kk) {
        const int kc = kk * 32 + q * 8;
        r.v[kk * 4 + 0] = *(const short8*)(wh + c0 * 128 + kc);
        r.v[kk * 4 + 1] = *(const short8*)(wh + c1 * 128 + kc);
        r.v[kk * 4 + 2] = *(const short8*)(wl + c0 * 128 + kc);
        r.v[kk * 4 + 3] = *(const short8*)(wl + c1 * 128 + kc);
    }
    return r;
}

// out[ROWS x 128] = act( in[ROWS x 128] @ W^T + bias ); ping-pong planes,
// one barrier per matvec. Weights for THIS matvec arrive preloaded in `w`;
// the NEXT matvec's weights are prefetched right after the barrier so their
// L2 latency hides behind this matvec's MFMAs + epilogue (r10: ~2.2us/matvec
// of exposed load latency was the fwd critical path).
// MODE 0: out = leaky(v) | 1: out = res + v | 2: out = leaky(v)+count | 3: count only
template<int MODE>
__device__ __forceinline__ W8 matvec(const W8& w,
        const unsigned short* inh, const unsigned short* inl,
        unsigned short* outh, unsigned short* outl,
        const unsigned short* resh, const unsigned short* resl,
        const unsigned short* __restrict__ nwh, const unsigned short* __restrict__ nwl,
        const float* __restrict__ bias,
        int lane, int colb, int* cnt) {
    const int m = lane & 15, q = lane >> 4;
    const int c0 = colb + m, c1 = colb + 16 + m;
    float b0 = bias[c0], b1v = bias[c1];
    float4f acc[2][2];
#pragma unroll
    for (int rt = 0; rt < 2; ++rt) {
        acc[rt][0] = (float4f){b0, b0, b0, b0};
        acc[rt][1] = (float4f){b1v, b1v, b1v, b1v};
    }
    __syncthreads();   // previous matvec's LDS writes visible; w's loads drained
    W8 wn = loadW(nwh, nwl, c0, c1, q);   // prefetch next matvec's weights
#pragma unroll
    for (int kk = 0; kk < 4; ++kk) {
        const int kc = kk * 32 + q * 8;
#pragma unroll
        for (int rt = 0; rt < 2; ++rt) {
            short8 xh = *(const short8*)(inh + (rt * 16 + m) * PITCH + kc);
            short8 xl = *(const short8*)(inl + (rt * 16 + m) * PITCH + kc);
            acc[rt][0] = mfma16(xh, w.v[kk * 4 + 0], acc[rt][0]);
            acc[rt][0] = mfma16(xl, w.v[kk * 4 + 0], acc[rt][0]);
            acc[rt][0] = mfma16(xh, w.v[kk * 4 + 2], acc[rt][0]);
            acc[rt][1] = mfma16(xh, w.v[kk * 4 + 1], acc[rt][1]);
            acc[rt][1] = mfma16(xl, w.v[kk * 4 + 1], acc[rt][1]);
            acc[rt][1] = mfma16(xh, w.v[kk * 4 + 3], acc[rt][1]);
        }
    }
    int c[2][4];
#pragma unroll
    for (int rt = 0; rt < 2; ++rt) {
#pragma unroll
        for (int r = 0; r < 4; ++r) {
            float v0 = acc[rt][0][r], v1 = acc[rt][1][r];
            int row = rt * 16 + q * 4 + r;
            int o0 = row * PITCH + c0, o1 = row * PITCH + c1;
            if (MODE == 1) {
                v0 += bf2f(resh[o0]) + bf2f(resl[o0]);
                v1 += bf2f(resh[o1]) + bf2f(resl[o1]);
            }
            if (MODE >= 2) c[rt][r] = (v0 <= 0.0f) + (v1 <= 0.0f);
            if (MODE == 0 || MODE == 2) {
                v0 = v0 > 0.0f ? v0 : 0.1f * v0;
                v1 = v1 > 0.0f ? v1 : 0.1f * v1;
            }
            if (MODE != 3) {
                unsigned short h0 = f2bf(v0);
                outh[o0] = h0; outl[o0] = f2bf(v0 - bf2f(h0));
                unsigned short h1 = f2bf(v1);
                outh[o1] = h1; outl[o1] = f2bf(v1 - bf2f(h1));
            }
        }
    }
    if (MODE >= 2) {
#pragma unroll
        for (int rt = 0; rt < 2; ++rt) {
#pragma unroll
            for (int r = 0; r < 4; ++r) {
                int cc = c[rt][r];
                cc += __shfl_xor(cc, 1);
                cc += __shfl_xor(cc, 2);
                cc += __shfl_xor(cc, 4);
                cc += __shfl_xor(cc, 8);
                if (m == 0) atomicAdd(&cnt[rt * 16 + q * 4 + r], cc);
            }
        }
    }
    return wn;
}

template<int ISF32>
__device__ __forceinline__ void fwd(int bid, int tid, int lane, char* ldsb,
                                    const void* x, const float* ws, void* out,
                                    float* wsw) {
    unsigned short* P = (unsigned short*)ldsb;
    unsigned short* Ah = P;
    unsigned short* Al = P + 1 * ROWS * PITCH;
    unsigned short* Bh = P + 2 * ROWS * PITCH;
    unsigned short* Bl = P + 3 * ROWS * PITCH;
    unsigned short* Th = P + 4 * ROWS * PITCH;
    unsigned short* Tl = P + 5 * ROWS * PITCH;
    unsigned short* Uh = P + 6 * ROWS * PITCH;
    unsigned short* Ul = P + 7 * ROWS * PITCH;
    int* cnt = (int*)(P + 8 * ROWS * PITCH);
    const unsigned short* whi = (const unsigned short*)(ws + WS_WPLANES);
    const unsigned short* wlo = whi + NWELEM;
    const float* bias = ws + WS_BIAS;
    const int r0 = bid * ROWS;
    const int m = lane & 15, q = lane >> 4;
    const int colb = (tid >> 6) * 32;
    const int c0 = colb + m, c1 = colb + 16 + m;
    // prefetch layer-0 w1 while staging x into LDS
    W8 wcur = loadW(whi, wlo, c0, c1, q);
    for (int e = tid; e < ROWS * 128; e += 256) {
        int r = e >> 7, c = e & 127;
        float v = ldv<ISF32>(x, (r0 + r) * 128 + c);
        unsigned short h = f2bf(v);
        Ah[r * PITCH + c] = h;
        Al[r * PITCH + c] = f2bf(v - bf2f(h));
    }
    if (tid < ROWS) cnt[tid] = 0;
    unsigned short *curh = Ah, *curl = Al, *othh = Bh, *othl = Bl;
#pragma unroll 1
    for (int layer = 0; layer < 4; ++layer) {
        const unsigned short* w1h = whi + (0 + layer) * 16384;
        const unsigned short* w1l = wlo + (0 + layer) * 16384;
        const unsigned short* w2h = whi + (4 + layer) * 16384;
        const unsigned short* w2l = wlo + (4 + layer) * 16384;
        const unsigned short* w3h = whi + (8 + layer) * 16384;
        const unsigned short* w3l = wlo + (8 + layer) * 16384;
        const unsigned short* n1h = whi + ((layer + 1) & 3) * 16384;  // next-layer w1
        const unsigned short* n1l = wlo + ((layer + 1) & 3) * 16384;
        const float* b1p = bias + layer * 128;
        const float* b2p = bias + 512 + layer * 128;
        const float* b3p = bias + 1024 + layer * 128;
        wcur = matvec<0>(wcur, curh, curl, Th, Tl, 0, 0, w2h, w2l, b1p, lane, colb, cnt);
        wcur = matvec<0>(wcur, Th, Tl, Uh, Ul, 0, 0, w3h, w3l, b2p, lane, colb, cnt);
        wcur = matvec<1>(wcur, Uh, Ul, othh, othl, curh, curl, w1h, w1l, b3p, lane, colb, cnt);
        wcur = matvec<2>(wcur, othh, othl, Th, Tl, 0, 0, w2h, w2l, b1p, lane, colb, cnt);
        wcur = matvec<3>(wcur, Th, Tl, Th, Tl, 0, 0, n1h, n1l, b2p, lane, colb, cnt);
        unsigned short* t;
        t = curh; curh = othh; othh = t;
        t = curl; curl = othl; othl = t;
    }
    __syncthreads();
    for (int e = tid; e < ROWS * 128; e += 256) {
        int r = e >> 7, c = e & 127;
        float v = bf2f(curh[r * PITCH + c]) + bf2f(curl[r * PITCH + c]);
        if (ISF32) ((float*)out)[(r0 + r) * 128 + c] = v;
        else ((unsigned short*)out)[(r0 + r) * 128 + c] = f2bf(v);
    }
    if (tid < ROWS) wsw[64 + r0 + tid] = (float)cnt[tid];
}

// ---- register-resident unpivoted LU, RANK-4 per barrier (32 intervals).
// Per interval: stage 4 pivot rows + 4 pivot cols (double-buffered LDS);
// every thread redundantly factors the 4x4 diagonal block in registers and
// applies one rank-4 update to its V[16]. All register indices compile-time.
template<int ISF32>
__device__ __forceinline__ float lu_logdet(int id, int tid, float* lds,
        const void* W1, const void* W2, const void* W3) {
    const int wsel = id % 3;
    const void* Wm = (wsel == 0 ? W1 : (wsel == 1 ? W2 : W3));
    const int ofs = (id / 3) * 16384;
    const int tx = tid & 31, ty = tid >> 5;
    float* rowbuf = lds;          // [2][4][128]: rows K..K+3
    float* colbuf = lds + 1024;   // [2][4][128]: cols K..K+3 packed [j][ty*16+m]
    float4f V[16];                // A[ty+8m][4tx..4tx+3]
#pragma unroll
    for (int m = 0; m < 16; ++m) {
        int base = ofs + (ty + 8 * m) * 128 + 4 * tx;
        if (ISF32) {
            V[m] = *(const float4f*)((const float*)Wm + base);
        } else {
            ushort4 u = *(const ushort4*)((const unsigned short*)Wm + base);
            V[m] = (float4f){bf2f(u.x), bf2f(u.y), bf2f(u.z), bf2f(u.w)};
        }
    }
    // stage interval 0: rows 0..3 (ty 0..3, all m=0), cols 0..3 (owner tx==0)
    if (ty < 4) *(float4f*)&rowbuf[ty * 128 + 4 * tx] = V[0];
    if (tx == 0) {
#pragma unroll
        for (int j = 0; j < 4; ++j) {
#pragma unroll
            for (int mg = 0; mg < 4; ++mg) {
                float4f t = {V[mg * 4 + 0][j], V[mg * 4 + 1][j],
                             V[mg * 4 + 2][j], V[mg * 4 + 3][j]};
                *(float4f*)&colbuf[j * 128 + ty * 16 + mg * 4] = t;
            }
        }
    }
    __syncthreads();
    float logacc = 0.0f;
#pragma unroll 1
    for (int kap = 0; kap < 32; ++kap) {
        const int K = kap * 4;
        const int buf = (kap & 1) * 512;
        float4f D[4], R[4], C[4][4];
#pragma unroll
        for (int j = 0; j < 4; ++j) {
            D[j] = *(const float4f*)&rowbuf[buf + j * 128 + K];       // broadcast
            R[j] = *(const float4f*)&rowbuf[buf + j * 128 + 4 * tx];
#pragma unroll
            for (int mg = 0; mg < 4; ++mg)
                C[j][mg] = *(const float4f*)&colbuf[buf + j * 128 + ty * 16 + mg * 4];
        }
        // 4x4 panel factorization, redundant per thread
        float p0 = D[0][0], i0 = 1.0f / p0;
        float l10 = D[1][0] * i0, l20 = D[2][0] * i0, l30 = D[3][0] * i0;
        D[1] = vmsub(D[1], l10, D[0]); R[1] = vmsub(R[1], l10, R[0]);
        D[2] = vmsub(D[2], l20, D[0]); R[2] = vmsub(R[2], l20, R[0]);
        D[3] = vmsub(D[3], l30, D[0]); R[3] = vmsub(R[3], l30, R[0]);
        float p1 = D[1][1], i1 = 1.0f / p1;
        float l21 = D[2][1] * i1, l31 = D[3][1] * i1;
        D[2] = vmsub(D[2], l21, D[1]); R[2] = vmsub(R[2], l21, R[1]);
        D[3] = vmsub(D[3], l31, D[1]); R[3] = vmsub(R[3], l31, R[1]);
        float p2 = D[2][2], i2 = 1.0f / p2;
        float l32 = D[3][2] * i2;
        D[3] = vmsub(D[3], l32, D[2]); R[3] = vmsub(R[3], l32, R[2]);
        float p3 = D[3][3], i3 = 1.0f / p3;
        logacc += __log2f(fabsf(p0)) + __log2f(fabsf(p1))
                + __log2f(fabsf(p2)) + __log2f(fabsf(p3));
        float iv[4] = {i0, i1, i2, i3};
        // cols -> multipliers in place (masked per row), propagate to later cols
#pragma unroll
        for (int i = 0; i < 4; ++i) {
#pragma unroll
            for (int mg = 0; mg < 4; ++mg) {
#pragma unroll
                for (int e = 0; e < 4; ++e) {
                    int r = ty + 32 * mg + 8 * e;
                    C[i][mg][e] = (r > K + i) ? C[i][mg][e] * iv[i] : 0.0f;
                }
            }
#pragma unroll
            for (int j = i + 1; j < 4; ++j) {
                float uij = D[i][j];
#pragma unroll
                for (int mg = 0; mg < 4; ++mg)
                    C[j][mg] = vmsub(C[j][mg], uij, C[i][mg]);
            }
        }
        // rank-4 trailing update
#pragma unroll
        for (int mg = 0; mg < 4; ++mg) {
#pragma unroll
            for (int e = 0; e < 4; ++e) {
                float4f v = V[mg * 4 + e];
                v = vmsub(v, C[0][mg][e], R[0]);
                v = vmsub(v, C[1][mg][e], R[1]);
                v = vmsub(v, C[2][mg][e], R[2]);
                v = vmsub(v, C[3][mg][e], R[3]);
                V[mg * 4 + e] = v;
            }
        }
        // stage next interval (rows/cols K+4..K+7)
        if (kap < 31) {
            const int nbuf = ((kap + 1) & 1) * 512;
            const int tb = (kap & 1) ? 0 : 4;     // rows K+4..K+7 -> ty in [tb,tb+4)
            const int mn = (kap + 1) >> 1;        // their m index (uniform)
            if (ty >= tb && ty < tb + 4) {
                float4f val;
                switch (mn) {                     // uniform switch, static reg index
                case 0:  val = V[0];  break; case 1:  val = V[1];  break;
                case 2:  val = V[2];  break; case 3:  val = V[3];  break;
                case 4:  val = V[4];  break; case 5:  val = V[5];  break;
                case 6:  val = V[6];  break; case 7:  val = V[7];  break;
                case 8:  val = V[8];  break; case 9:  val = V[9];  break;
                case 10: val = V[10]; break; case 11: val = V[11]; break;
                case 12: val = V[12]; break; case 13: val = V[13]; break;
                case 14: val = V[14]; break; default: val = V[15]; break;
                }
                *(float4f*)&rowbuf[nbuf + (ty - tb) * 128 + 4 * tx] = val;
            }
            if (tx == kap + 1) {   // owner of cols K+4..K+7 (4-aligned)
#pragma unroll
                for (int j = 0; j < 4; ++j) {
#pragma unroll
                    for (int mg = 0; mg < 4; ++mg) {
                        float4f t = {V[mg * 4 + 0][j], V[mg * 4 + 1][j],
                                     V[mg * 4 + 2][j], V[mg * 4 + 3][j]};
                        *(float4f*)&colbuf[nbuf + j * 128 + ty * 16 + mg * 4] = t;
                    }
                }
            }
        }
        __syncthreads();   // one barrier per 4 pivots
    }
    return logacc * LN2;
}

__global__ __launch_bounds__(256) void k_main(
        const void* __restrict__ x,
        const void* __restrict__ W1, const void* __restrict__ b1,
        const void* __restrict__ W2, const void* __restrict__ b2,
        const void* __restrict__ W3, const void* __restrict__ b3,
        void* __restrict__ out, float* __restrict__ ws) {
    extern __shared__ __align__(16) char ldsb[];
    __shared__ int s_last;
    const int tid = threadIdx.x;
    const int lane = tid & 63;
    const int isf32 = detect_f32((const unsigned short*)W1, lane);

    if (blockIdx.x < 12) {
        float ld = isf32 ? lu_logdet<1>(blockIdx.x, tid, (float*)ldsb, W1, W2, W3)
                         : lu_logdet<0>(blockIdx.x, tid, (float*)ldsb, W1, W2, W3);
        if (tid == 0) ws[2 + blockIdx.x] = ld;
    } else {
        const int bid = blockIdx.x - 12;
        if (isf32) fwd<1>(bid, tid, lane, ldsb, x, ws, out, ws);
        else       fwd<0>(bid, tid, lane, ldsb, x, ws, out, ws);
    }

    // ---- last-block finalize ----
    __threadfence();
    if (tid == 0) s_last = (atomicAdd((int*)ws, 1) == NBLK - 1);
    __syncthreads();
    if (!s_last) return;
    __threadfence();   // acquire: other blocks' ws writes now visible
    float s = 0.0f;
#pragma unroll
    for (int i = 0; i < 12; ++i) s += ws[2 + i];
    for (int b = tid; b < 4096; b += 256) {
        float v = s + LOG_SLOPE * ws[64 + b];
        if (isf32) ((float*)out)[524288 + b] = v;
        else ((unsigned short*)out)[524288 + b] = f2bf(v);
    }
}

extern "C" void kernel_launch(void* const* d_in, const int* in_sizes, int n_in,
                              void* d_out, int out_size, void* d_ws, size_t ws_size,
                              hipStream_t stream) {
    const void* x  = d_in[0];
    const void* W1 = d_in[1];
    const void* b1 = d_in[2];
    const void* W2 = d_in[3];
    const void* b2 = d_in[4];
    const void* W3 = d_in[5];
    const void* b3 = d_in[6];
    float* ws = (float*)d_ws;

    hipLaunchKernelGGL(k_prep, dim3(97), dim3(256), 0, stream,
                       W1, W2, W3, b1, b2, b3, ws);
    hipLaunchKernelGGL(k_main, dim3(NBLK), dim3(256), LDS_BYTES, stream,
                       x, W1, b1, W2, b2, W3, b3, d_out, ws);
}